// Round 1
// baseline (371.356 us; speedup 1.0000x reference)
//
#include <hip/hip_runtime.h>
#include <math.h>

#define NB 4
#define IH 128
#define IW 128
#define GH 256
#define GW 256

// d_ws layout (floats):
// [0, 786432)            accum  (B, GH, GW, 3)
// [786432, 789024)       W_eff  [4][24][27]
// [789024, 789120)       b_eff  [4][24]
#define ACCUM_FLOATS (NB * GH * GW * 3)
#define WEFF_FLOATS (4 * 24 * 27)
#define BEFF_FLOATS (4 * 24)

__global__ __launch_bounds__(256) void weff_kernel(
    const float* __restrict__ w_enc, const float* __restrict__ b_enc,
    const float* __restrict__ w_head, const float* __restrict__ b_head,
    float* __restrict__ weff, float* __restrict__ beff) {
  int idx = blockIdx.x * blockDim.x + threadIdx.x;
  if (idx < WEFF_FLOATS) {
    int p = idx / (24 * 27);
    int rem = idx % (24 * 27);
    int o = rem / 27;
    int t = rem % 27;  // cin*9 + ky*3 + kx
    int ph = p >> 1, pw = p & 1;
    float acc = 0.f;
    for (int c64 = 0; c64 < 64; ++c64) {
      #pragma unroll
      for (int i2 = 0; i2 < 2; ++i2) {
        #pragma unroll
        for (int j2 = 0; j2 < 2; ++j2) {
          int hc = c64 * 4 + i2 * 2 + j2;                    // w_head column
          int ch = c64 * 16 + (2 * ph + i2) * 4 + (2 * pw + j2);  // conv out channel
          acc += w_head[o * 256 + hc] * w_enc[ch * 27 + t];
        }
      }
    }
    weff[idx] = acc;
  }
  if (idx < BEFF_FLOATS) {
    int p = idx / 24, o = idx % 24;
    int ph = p >> 1, pw = p & 1;
    float acc = b_head[o];
    for (int c64 = 0; c64 < 64; ++c64) {
      #pragma unroll
      for (int i2 = 0; i2 < 2; ++i2) {
        #pragma unroll
        for (int j2 = 0; j2 < 2; ++j2) {
          int hc = c64 * 4 + i2 * 2 + j2;
          int ch = c64 * 16 + (2 * ph + i2) * 4 + (2 * pw + j2);
          acc += w_head[o * 256 + hc] * b_enc[ch];
        }
      }
    }
    beff[idx] = acc;
  }
}

__global__ __launch_bounds__(256) void splat_kernel(
    const float* __restrict__ inp, const float* __restrict__ weff,
    const float* __restrict__ beff, float* __restrict__ accum) {
  __shared__ float sW[WEFF_FLOATS];
  __shared__ float sB[BEFF_FLOATS];
  for (int i = threadIdx.x; i < WEFF_FLOATS; i += 256) sW[i] = weff[i];
  for (int i = threadIdx.x; i < BEFF_FLOATS; i += 256) sB[i] = beff[i];
  __syncthreads();

  int tid = (int)threadIdx.x;
  int ws = tid & 127;
  int hs = ((int)blockIdx.x & 63) * 2 + (tid >> 7);
  int b = (int)blockIdx.x >> 6;

  // Load the 3x3x3 input patch (SAME zero padding).
  float in[27];
  const float* ib = inp + b * 3 * IH * IW;
  #pragma unroll
  for (int cin = 0; cin < 3; ++cin) {
    #pragma unroll
    for (int ky = 0; ky < 3; ++ky) {
      int y = hs + ky - 1;
      #pragma unroll
      for (int kx = 0; kx < 3; ++kx) {
        int x = ws + kx - 1;
        float v = 0.f;
        if (y >= 0 && y < IH && x >= 0 && x < IW) v = ib[(cin * IH + y) * IW + x];
        in[cin * 9 + ky * 3 + kx] = v;
      }
    }
  }

  float* acc_b = accum + b * GH * GW * 3;

  for (int p = 0; p < 4; ++p) {
    int ph = p >> 1, pw = p & 1;
    float pr[24];
    #pragma unroll
    for (int o = 0; o < 24; ++o) {
      float a = sB[p * 24 + o];
      const float* w = &sW[(p * 24 + o) * 27];
      #pragma unroll
      for (int t = 0; t < 27; ++t) a = fmaf(in[t], w[t], a);
      pr[o] = a;
    }
    // softmax over K=4 of the weight logits pr[k*6+5]
    float l0 = pr[5], l1 = pr[11], l2 = pr[17], l3 = pr[23];
    float m = fmaxf(fmaxf(l0, l1), fmaxf(l2, l3));
    float e0 = expf(l0 - m), e1 = expf(l1 - m), e2 = expf(l2 - m), e3 = expf(l3 - m);
    float s = e0 + e1 + e2 + e3;
    float inv = 1.f / s;
    float w0 = e0 * inv, w1 = e1 * inv, w2 = e2 * inv, w3 = e3 * inv;
    float cr = w0 * pr[0] + w1 * pr[6] + w2 * pr[12] + w3 * pr[18];
    float cg = w0 * pr[1] + w1 * pr[7] + w2 * pr[13] + w3 * pr[19];
    float cb = w0 * pr[2] + w1 * pr[8] + w2 * pr[14] + w3 * pr[20];
    float ox = w0 * tanhf(pr[3]) + w1 * tanhf(pr[9]) + w2 * tanhf(pr[15]) + w3 * tanhf(pr[21]);
    float oy = w0 * tanhf(pr[4]) + w1 * tanhf(pr[10]) + w2 * tanhf(pr[16]) + w3 * tanhf(pr[22]);

    int ww = 2 * ws + pw, hh = 2 * hs + ph;
    // reference-order coordinate math (w=h=128, W=H=gw=gh=256)
    float coordx = ((float)ww / 256.f) * 2.f - 1.f;
    float coordy = ((float)hh / 256.f) * 2.f - 1.f;
    float x_ndc = coordx + 2.f * ox / 128.f - 1.f / 256.f;
    float y_ndc = coordy + 2.f * oy / 128.f - 1.f / 256.f;
    float cx = 0.5f * ((x_ndc + 1.f) * 256.f - 1.f);
    float cy = 0.5f * ((y_ndc + 1.f) * 256.f - 1.f);
    float fx = floorf(cx), fy = floorf(cy);

    #pragma unroll
    for (int oyi = -2; oyi <= 2; ++oyi) {
      float py = fy + (float)oyi;
      int pyi = (int)py;
      if (pyi < 0 || pyi >= GH) continue;
      float dy = py - cy;
      float dy2 = dy * dy;
      #pragma unroll
      for (int oxi = -2; oxi <= 2; ++oxi) {
        float px = fx + (float)oxi;
        int pxi = (int)px;
        if (pxi < 0 || pxi >= GW) continue;
        float dx = px - cx;
        float power = -2.f * (dx * dx + dy2);  // -0.5/(0.5^2) = -2
        float alpha = fminf(0.999f, expf(power));
        if (alpha > (1.f / 255.f)) {
          float* dst = acc_b + (pyi * GW + pxi) * 3;
          atomicAdd(dst + 0, alpha * cr);
          atomicAdd(dst + 1, alpha * cg);
          atomicAdd(dst + 2, alpha * cb);
        }
      }
    }
  }
}

__global__ __launch_bounds__(256) void finalize_kernel(
    const float* __restrict__ accum, float* __restrict__ out) {
  int idx = blockIdx.x * blockDim.x + threadIdx.x;
  if (idx >= NB * 3 * GH * GW) return;
  int x = idx & (GW - 1);
  int y = (idx >> 8) & (GH - 1);
  int c = (idx >> 16) % 3;
  int b = idx / (3 * GH * GW);
  float v = accum[((b * GH + y) * GW + x) * 3 + c];
  out[idx] = fminf(1.f, fmaxf(0.f, v));
}

extern "C" void kernel_launch(void* const* d_in, const int* in_sizes, int n_in,
                              void* d_out, int out_size, void* d_ws, size_t ws_size,
                              hipStream_t stream) {
  const float* inp = (const float*)d_in[0];
  const float* w_enc = (const float*)d_in[1];
  const float* b_enc = (const float*)d_in[2];
  const float* w_head = (const float*)d_in[3];
  const float* b_head = (const float*)d_in[4];
  // d_in[5] = scale (int), hardcoded 2.

  float* accum = (float*)d_ws;
  float* weff = accum + ACCUM_FLOATS;
  float* beff = weff + WEFF_FLOATS;
  float* out = (float*)d_out;

  hipMemsetAsync(accum, 0, ACCUM_FLOATS * sizeof(float), stream);

  weff_kernel<<<(WEFF_FLOATS + 255) / 256, 256, 0, stream>>>(w_enc, b_enc, w_head, b_head,
                                                             weff, beff);

  splat_kernel<<<NB * 64, 256, 0, stream>>>(inp, weff, beff, accum);

  finalize_kernel<<<(NB * 3 * GH * GW + 255) / 256, 256, 0, stream>>>(accum, out);
}

// Round 3
// 141.933 us; speedup vs baseline: 2.6164x; 2.6164x over previous
//
#include <hip/hip_runtime.h>
#include <math.h>

#define NB 4
#define IH 128
#define IW 128
#define GH 256
#define GW 256

// Output tiling for the splat kernel
#define TS 32                 // output-pixel tile side
#define HALO_LO 5             // gaussian reach: py in [hh-5, hh+3]
#define LT (TS + 8)           // 40: LDS tile side (covers [-5, +34])
#define LDS_TILE (LT * LT * 3)

// d_ws layout (floats):
// [0, 786432)            accum  (B, GH, GW, 3)
// [786432, 789024)       W_eff  [4][24][27]
// [789024, 789120)       b_eff  [4][24]
#define ACCUM_FLOATS (NB * GH * GW * 3)
#define WEFF_FLOATS (4 * 24 * 27)
#define BEFF_FLOATS (4 * 24)

__device__ __forceinline__ float fast_tanh(float x) {
  // tanh(x) = 1 - 2/(exp(2x)+1); __expf -> v_exp_f32
  return 1.f - 2.f / (__expf(2.f * x) + 1.f);
}

__global__ __launch_bounds__(256) void weff_kernel(
    const float* __restrict__ w_enc, const float* __restrict__ b_enc,
    const float* __restrict__ w_head, const float* __restrict__ b_head,
    float* __restrict__ weff, float* __restrict__ beff) {
  int idx = blockIdx.x * blockDim.x + threadIdx.x;
  if (idx < WEFF_FLOATS) {
    int p = idx / (24 * 27);
    int rem = idx % (24 * 27);
    int o = rem / 27;
    int t = rem % 27;  // cin*9 + ky*3 + kx
    int ph = p >> 1, pw = p & 1;
    float acc = 0.f;
    for (int c64 = 0; c64 < 64; ++c64) {
      #pragma unroll
      for (int i2 = 0; i2 < 2; ++i2) {
        #pragma unroll
        for (int j2 = 0; j2 < 2; ++j2) {
          int hc = c64 * 4 + i2 * 2 + j2;                         // w_head column
          int ch = c64 * 16 + (2 * ph + i2) * 4 + (2 * pw + j2);  // conv out channel
          acc += w_head[o * 256 + hc] * w_enc[ch * 27 + t];
        }
      }
    }
    weff[idx] = acc;
  }
  if (idx < BEFF_FLOATS) {
    int p = idx / 24, o = idx % 24;
    int ph = p >> 1, pw = p & 1;
    float acc = b_head[o];
    for (int c64 = 0; c64 < 64; ++c64) {
      #pragma unroll
      for (int i2 = 0; i2 < 2; ++i2) {
        #pragma unroll
        for (int j2 = 0; j2 < 2; ++j2) {
          int hc = c64 * 4 + i2 * 2 + j2;
          int ch = c64 * 16 + (2 * ph + i2) * 4 + (2 * pw + j2);
          acc += w_head[o * 256 + hc] * b_enc[ch];
        }
      }
    }
    beff[idx] = acc;
  }
}

// One block per 32x32 output tile: compute 16x16 conv locations (1/thread),
// splat all 4 sub-pixel gaussians into an LDS tile with ds atomics, then
// flush the tile to the global accumulator with coalesced atomics.
__global__ __launch_bounds__(256) void splat_kernel(
    const float* __restrict__ inp, const float* __restrict__ weff,
    const float* __restrict__ beff, float* __restrict__ accum) {
  __shared__ float sW[WEFF_FLOATS];
  __shared__ float sB[BEFF_FLOATS];
  __shared__ float sTile[LDS_TILE];

  int tid = (int)threadIdx.x;
  for (int i = tid; i < WEFF_FLOATS; i += 256) sW[i] = weff[i];
  for (int i = tid; i < BEFF_FLOATS; i += 256) sB[i] = beff[i];
  for (int i = tid; i < LDS_TILE; i += 256) sTile[i] = 0.f;
  __syncthreads();

  int bid = (int)blockIdx.x;
  int b = bid >> 6;           // batch
  int tileid = bid & 63;      // 8x8 tiles
  int OY = (tileid >> 3) * TS;
  int OX = (tileid & 7) * TS;

  // conv location for this thread
  int ls_y = tid >> 4, ls_x = tid & 15;
  int hs = (OY >> 1) + ls_y;
  int ws = (OX >> 1) + ls_x;

  // Load the 3x3x3 input patch (SAME zero padding).
  float in[27];
  const float* ib = inp + b * 3 * IH * IW;
  #pragma unroll
  for (int cin = 0; cin < 3; ++cin) {
    #pragma unroll
    for (int ky = 0; ky < 3; ++ky) {
      int y = hs + ky - 1;
      #pragma unroll
      for (int kx = 0; kx < 3; ++kx) {
        int x = ws + kx - 1;
        float v = 0.f;
        if (y >= 0 && y < IH && x >= 0 && x < IW) v = ib[(cin * IH + y) * IW + x];
        in[cin * 9 + ky * 3 + kx] = v;
      }
    }
  }

  for (int p = 0; p < 4; ++p) {
    int ph = p >> 1, pw = p & 1;
    float pr[24];
    #pragma unroll
    for (int o = 0; o < 24; ++o) {
      float a = sB[p * 24 + o];
      const float* w = &sW[(p * 24 + o) * 27];
      #pragma unroll
      for (int t = 0; t < 27; ++t) a = fmaf(in[t], w[t], a);
      pr[o] = a;
    }
    // softmax over K=4 of the weight logits pr[k*6+5]
    float l0 = pr[5], l1 = pr[11], l2 = pr[17], l3 = pr[23];
    float m = fmaxf(fmaxf(l0, l1), fmaxf(l2, l3));
    float e0 = __expf(l0 - m), e1 = __expf(l1 - m), e2 = __expf(l2 - m), e3 = __expf(l3 - m);
    float inv = 1.f / (e0 + e1 + e2 + e3);
    float w0 = e0 * inv, w1 = e1 * inv, w2 = e2 * inv, w3 = e3 * inv;
    float cr = w0 * pr[0] + w1 * pr[6] + w2 * pr[12] + w3 * pr[18];
    float cg = w0 * pr[1] + w1 * pr[7] + w2 * pr[13] + w3 * pr[19];
    float cb = w0 * pr[2] + w1 * pr[8] + w2 * pr[14] + w3 * pr[20];
    float ox = w0 * fast_tanh(pr[3]) + w1 * fast_tanh(pr[9]) +
               w2 * fast_tanh(pr[15]) + w3 * fast_tanh(pr[21]);
    float oy = w0 * fast_tanh(pr[4]) + w1 * fast_tanh(pr[10]) +
               w2 * fast_tanh(pr[16]) + w3 * fast_tanh(pr[22]);

    int ww = 2 * ws + pw, hh = 2 * hs + ph;
    // reference-order coordinate math (w=h=128, W=H=gw=gh=256)
    float coordx = ((float)ww / 256.f) * 2.f - 1.f;
    float coordy = ((float)hh / 256.f) * 2.f - 1.f;
    float x_ndc = coordx + 2.f * ox / 128.f - 1.f / 256.f;
    float y_ndc = coordy + 2.f * oy / 128.f - 1.f / 256.f;
    float cx = 0.5f * ((x_ndc + 1.f) * 256.f - 1.f);
    float cy = 0.5f * ((y_ndc + 1.f) * 256.f - 1.f);
    float fx = floorf(cx), fy = floorf(cy);

    // LDS-local base (image-bound clipping deferred to the flush)
    int by = (int)fy - (OY - HALO_LO);
    int bx = (int)fx - (OX - HALO_LO);

    #pragma unroll
    for (int oyi = -2; oyi <= 2; ++oyi) {
      float dy = (fy + (float)oyi) - cy;
      float dy2 = dy * dy;
      int ly = by + oyi;
      #pragma unroll
      for (int oxi = -2; oxi <= 2; ++oxi) {
        float dx = (fx + (float)oxi) - cx;
        float power = -2.f * (dx * dx + dy2);  // -0.5 / (0.25*2)^2 = -2
        float alpha = fminf(0.999f, __expf(power));
        if (alpha > (1.f / 255.f)) {
          int lx = bx + oxi;
          float* dst = &sTile[(ly * LT + lx) * 3];
          atomicAdd(dst + 0, alpha * cr);
          atomicAdd(dst + 1, alpha * cg);
          atomicAdd(dst + 2, alpha * cb);
        }
      }
    }
  }

  __syncthreads();

  // Flush LDS tile to global accumulator (coalesced atomics; halo overlaps
  // neighbor tiles so atomics are required).
  float* acc_b = accum + b * GH * GW * 3;
  for (int i = tid; i < LDS_TILE; i += 256) {
    float v = sTile[i];
    if (v == 0.f) continue;
    int cell = i / 3, c = i - cell * 3;
    int ly = cell / LT, lx = cell - ly * LT;
    int gy = OY - HALO_LO + ly;
    int gx = OX - HALO_LO + lx;
    if (gy < 0 || gy >= GH || gx < 0 || gx >= GW) continue;
    atomicAdd(acc_b + (gy * GW + gx) * 3 + c, v);
  }
}

__global__ __launch_bounds__(256) void finalize_kernel(
    const float* __restrict__ accum, float* __restrict__ out) {
  int idx = blockIdx.x * blockDim.x + threadIdx.x;
  if (idx >= NB * 3 * GH * GW) return;
  int x = idx & (GW - 1);
  int y = (idx >> 8) & (GH - 1);
  int c = (idx >> 16) % 3;
  int b = idx / (3 * GH * GW);
  float v = accum[((b * GH + y) * GW + x) * 3 + c];
  out[idx] = fminf(1.f, fmaxf(0.f, v));
}

extern "C" void kernel_launch(void* const* d_in, const int* in_sizes, int n_in,
                              void* d_out, int out_size, void* d_ws, size_t ws_size,
                              hipStream_t stream) {
  const float* inp = (const float*)d_in[0];
  const float* w_enc = (const float*)d_in[1];
  const float* b_enc = (const float*)d_in[2];
  const float* w_head = (const float*)d_in[3];
  const float* b_head = (const float*)d_in[4];
  // d_in[5] = scale (int), hardcoded 2.

  float* accum = (float*)d_ws;
  float* weff = accum + ACCUM_FLOATS;
  float* beff = weff + WEFF_FLOATS;
  float* out = (float*)d_out;

  hipMemsetAsync(accum, 0, ACCUM_FLOATS * sizeof(float), stream);

  weff_kernel<<<(WEFF_FLOATS + 255) / 256, 256, 0, stream>>>(w_enc, b_enc, w_head, b_head,
                                                             weff, beff);

  splat_kernel<<<NB * 64, 256, 0, stream>>>(inp, weff, beff, accum);

  finalize_kernel<<<(NB * 3 * GH * GW + 255) / 256, 256, 0, stream>>>(accum, out);
}

// Round 4
// 130.926 us; speedup vs baseline: 2.8364x; 1.0841x over previous
//
#include <hip/hip_runtime.h>
#include <math.h>

#define NB 4
#define IH 128
#define IW 128
#define GH 256
#define GW 256

// Splat tiling: 16x16 output-pixel tiles, halo [-5, +3] in both axes.
#define TS 16
#define HALO_LO 5
#define LT 24                  // TS + 8 live cells
#define LTP 25                 // padded row stride (breaks mod-32 bank aliasing)
#define STILE_FLOATS (3 * LTP * LTP)

// d_ws layout (floats):
// [0, 786432)            accum  (B, 3, GH, GW)  -- CHW planar, matches d_out
// [786432, 789024)       W_eff  [4][24][27]     -- p = ph*2+pw
// [789024, 789120)       b_eff  [4][24]
#define ACCUM_FLOATS (NB * 3 * GH * GW)
#define WEFF_FLOATS (4 * 24 * 27)
#define BEFF_FLOATS (4 * 24)

__device__ __forceinline__ float fast_tanh(float x) {
  return 1.f - 2.f / (__expf(2.f * x) + 1.f);
}

// One block per parity p: fold w_head x (pixel ops) x w_enc into
// W_eff[p][24][27], b_eff[p][24]. All loads coalesced, math from LDS.
__global__ __launch_bounds__(256) void weff_kernel(
    const float* __restrict__ w_enc, const float* __restrict__ b_enc,
    const float* __restrict__ w_head, const float* __restrict__ b_head,
    float* __restrict__ weff, float* __restrict__ beff) {
  __shared__ float sWH[24 * 256];   // w_head, row o
  __shared__ float sWE[256 * 27];   // selected conv channels, row hc
  __shared__ float sBE[256];        // b_enc[ch(hc)]

  int tid = (int)threadIdx.x;
  int p = (int)blockIdx.x;          // p = ph*2 + pw
  int ph = p >> 1, pw = p & 1;

  for (int i = tid; i < 24 * 256; i += 256) sWH[i] = w_head[i];
  {
    // thread tid owns head-column hc = tid; conv channel:
    int hc = tid;
    int ch = ((hc >> 2) << 4) + (2 * ph + ((hc >> 1) & 1)) * 4 + (2 * pw + (hc & 1));
    for (int t = 0; t < 27; ++t) sWE[hc * 27 + t] = w_enc[ch * 27 + t];
    sBE[hc] = b_enc[ch];
  }
  __syncthreads();

  for (int j = tid; j < 24 * 27; j += 256) {
    int o = j / 27, t = j % 27;
    float a = 0.f;
    for (int hc = 0; hc < 256; ++hc) a = fmaf(sWH[o * 256 + hc], sWE[hc * 27 + t], a);
    weff[p * (24 * 27) + j] = a;
  }
  if (tid < 24) {
    float a = b_head[tid];
    for (int hc = 0; hc < 256; ++hc) a = fmaf(sWH[tid * 256 + hc], sBE[hc], a);
    beff[p * 24 + tid] = a;
  }
}

// One block per (batch, 16x16 output tile). thread = (parity, 8x8 conv loc).
// Splat into padded planar LDS tile with ds atomics, flush coalesced.
__global__ __launch_bounds__(256) void splat_kernel(
    const float* __restrict__ inp, const float* __restrict__ weff,
    const float* __restrict__ beff, float* __restrict__ accum) {
  __shared__ float sW[WEFF_FLOATS];
  __shared__ float sB[BEFF_FLOATS];
  __shared__ float sTile[STILE_FLOATS];

  int tid = (int)threadIdx.x;
  for (int i = tid; i < WEFF_FLOATS; i += 256) sW[i] = weff[i];
  for (int i = tid; i < BEFF_FLOATS; i += 256) sB[i] = beff[i];
  for (int i = tid; i < STILE_FLOATS; i += 256) sTile[i] = 0.f;
  __syncthreads();

  int bid = (int)blockIdx.x;
  int b = bid >> 8;                 // batch
  int tileid = bid & 255;           // 16x16 tiles of 16px
  int TY = (tileid >> 4) * TS;
  int TX = (tileid & 15) * TS;

  int p = tid >> 6;                 // parity (= wave id)
  int ph = p >> 1, pw = p & 1;
  int loc = tid & 63;
  int hs = (TY >> 1) + (loc >> 3);
  int ws = (TX >> 1) + (loc & 7);

  // 3x3x3 input patch (SAME zero padding)
  float in[27];
  const float* ib = inp + b * 3 * IH * IW;
  #pragma unroll
  for (int cin = 0; cin < 3; ++cin) {
    #pragma unroll
    for (int ky = 0; ky < 3; ++ky) {
      int y = hs + ky - 1;
      #pragma unroll
      for (int kx = 0; kx < 3; ++kx) {
        int x = ws + kx - 1;
        float v = 0.f;
        if (y >= 0 && y < IH && x >= 0 && x < IW) v = ib[(cin * IH + y) * IW + x];
        in[cin * 9 + ky * 3 + kx] = v;
      }
    }
  }

  float pr[24];
  #pragma unroll
  for (int o = 0; o < 24; ++o) {
    float a = sB[p * 24 + o];
    const float* w = &sW[(p * 24 + o) * 27];
    #pragma unroll
    for (int t = 0; t < 27; ++t) a = fmaf(in[t], w[t], a);
    pr[o] = a;
  }

  float l0 = pr[5], l1 = pr[11], l2 = pr[17], l3 = pr[23];
  float m = fmaxf(fmaxf(l0, l1), fmaxf(l2, l3));
  float e0 = __expf(l0 - m), e1 = __expf(l1 - m), e2 = __expf(l2 - m), e3 = __expf(l3 - m);
  float inv = 1.f / (e0 + e1 + e2 + e3);
  float w0 = e0 * inv, w1 = e1 * inv, w2 = e2 * inv, w3 = e3 * inv;
  float cr = w0 * pr[0] + w1 * pr[6] + w2 * pr[12] + w3 * pr[18];
  float cg = w0 * pr[1] + w1 * pr[7] + w2 * pr[13] + w3 * pr[19];
  float cb = w0 * pr[2] + w1 * pr[8] + w2 * pr[14] + w3 * pr[20];
  float ox = w0 * fast_tanh(pr[3]) + w1 * fast_tanh(pr[9]) +
             w2 * fast_tanh(pr[15]) + w3 * fast_tanh(pr[21]);
  float oy = w0 * fast_tanh(pr[4]) + w1 * fast_tanh(pr[10]) +
             w2 * fast_tanh(pr[16]) + w3 * fast_tanh(pr[22]);

  int ww = 2 * ws + pw, hh = 2 * hs + ph;
  // reference-order coordinate math (w=h=128, W=H=gw=gh=256)
  float coordx = ((float)ww / 256.f) * 2.f - 1.f;
  float coordy = ((float)hh / 256.f) * 2.f - 1.f;
  float x_ndc = coordx + 2.f * ox / 128.f - 1.f / 256.f;
  float y_ndc = coordy + 2.f * oy / 128.f - 1.f / 256.f;
  float cx = 0.5f * ((x_ndc + 1.f) * 256.f - 1.f);
  float cy = 0.5f * ((y_ndc + 1.f) * 256.f - 1.f);
  float fx = floorf(cx), fy = floorf(cy);

  int by = (int)fy - (TY - HALO_LO);
  int bx = (int)fx - (TX - HALO_LO);

  #pragma unroll
  for (int oyi = -2; oyi <= 2; ++oyi) {
    float dy = (fy + (float)oyi) - cy;
    float dy2 = dy * dy;
    int ly = by + oyi;
    #pragma unroll
    for (int oxi = -2; oxi <= 2; ++oxi) {
      float dx = (fx + (float)oxi) - cx;
      float power = -2.f * (dx * dx + dy2);  // -0.5 / (0.25*2)^2 = -2
      float alpha = fminf(0.999f, __expf(power));
      if (alpha > (1.f / 255.f)) {
        int lx = bx + oxi;
        float* dst = &sTile[ly * LTP + lx];
        atomicAdd(dst, alpha * cr);
        atomicAdd(dst + LTP * LTP, alpha * cg);
        atomicAdd(dst + 2 * LTP * LTP, alpha * cb);
      }
    }
  }

  __syncthreads();

  // Flush live 24x24x3 region to CHW global accumulator, coalesced.
  for (int i = tid; i < 3 * LT * LT; i += 256) {
    int c = i / (LT * LT);
    int r = i - c * (LT * LT);
    int ly = r / LT, lx = r - ly * LT;
    float v = sTile[(c * LTP + ly) * LTP + lx];
    if (v == 0.f) continue;
    int gy = TY - HALO_LO + ly;
    int gx = TX - HALO_LO + lx;
    if (gy < 0 || gy >= GH || gx < 0 || gx >= GW) continue;
    atomicAdd(accum + ((b * 3 + c) * GH + gy) * GW + gx, v);
  }
}

// accum (CHW) indexing == out indexing: pure vector clamp-copy.
__global__ __launch_bounds__(256) void finalize_kernel(
    const float4* __restrict__ accum, float4* __restrict__ out) {
  int idx = blockIdx.x * blockDim.x + threadIdx.x;
  if (idx >= ACCUM_FLOATS / 4) return;
  float4 v = accum[idx];
  v.x = fminf(1.f, fmaxf(0.f, v.x));
  v.y = fminf(1.f, fmaxf(0.f, v.y));
  v.z = fminf(1.f, fmaxf(0.f, v.z));
  v.w = fminf(1.f, fmaxf(0.f, v.w));
  out[idx] = v;
}

extern "C" void kernel_launch(void* const* d_in, const int* in_sizes, int n_in,
                              void* d_out, int out_size, void* d_ws, size_t ws_size,
                              hipStream_t stream) {
  const float* inp = (const float*)d_in[0];
  const float* w_enc = (const float*)d_in[1];
  const float* b_enc = (const float*)d_in[2];
  const float* w_head = (const float*)d_in[3];
  const float* b_head = (const float*)d_in[4];
  // d_in[5] = scale (int), hardcoded 2.

  float* accum = (float*)d_ws;
  float* weff = accum + ACCUM_FLOATS;
  float* beff = weff + WEFF_FLOATS;

  hipMemsetAsync(accum, 0, ACCUM_FLOATS * sizeof(float), stream);

  weff_kernel<<<4, 256, 0, stream>>>(w_enc, b_enc, w_head, b_head, weff, beff);

  splat_kernel<<<NB * 256, 256, 0, stream>>>(inp, weff, beff, accum);

  finalize_kernel<<<(ACCUM_FLOATS / 4 + 255) / 256, 256, 0, stream>>>(
      (const float4*)accum, (float4*)d_out);
}

// Round 6
// 112.963 us; speedup vs baseline: 3.2874x; 1.1590x over previous
//
#include <hip/hip_runtime.h>
#include <math.h>

#define NB 4
#define IH 128
#define IW 128
#define GH 256
#define GW 256

// Gather tiling: each block renders a 16(x) x 32(y) pixel tile.
// Contributing gaussians: x in [TX-3, TX+20] (24), y in [TY-3, TY+36] (40).
#define TSX 16
#define TSY 32
#define GRX 24
#define GRY 40
#define NG (GRX * GRY)   // 960

// d_ws layout (floats): W_eff [4][24][27], b_eff [4][24]
#define WEFF_FLOATS (4 * 24 * 27)
#define BEFF_FLOATS (4 * 24)

__device__ __forceinline__ float fast_tanh(float x) {
  return 1.f - 2.f / (__expf(2.f * x) + 1.f);
}
__device__ __forceinline__ float clamp01(float v) {
  return fminf(1.f, fmaxf(0.f, v));
}

// One block per parity p: fold w_head x (pixel ops) x w_enc into
// W_eff[p][24][27], b_eff[p][24]. All loads coalesced, math from LDS.
__global__ __launch_bounds__(256) void weff_kernel(
    const float* __restrict__ w_enc, const float* __restrict__ b_enc,
    const float* __restrict__ w_head, const float* __restrict__ b_head,
    float* __restrict__ weff, float* __restrict__ beff) {
  __shared__ float sWH[24 * 256];
  __shared__ float sWE[256 * 27];
  __shared__ float sBE[256];

  int tid = (int)threadIdx.x;
  int p = (int)blockIdx.x;          // p = ph*2 + pw
  int ph = p >> 1, pw = p & 1;

  for (int i = tid; i < 24 * 256; i += 256) sWH[i] = w_head[i];
  {
    int hc = tid;
    int ch = ((hc >> 2) << 4) + (2 * ph + ((hc >> 1) & 1)) * 4 + (2 * pw + (hc & 1));
    for (int t = 0; t < 27; ++t) sWE[hc * 27 + t] = w_enc[ch * 27 + t];
    sBE[hc] = b_enc[ch];
  }
  __syncthreads();

  for (int j = tid; j < 24 * 27; j += 256) {
    int o = j / 27, t = j % 27;
    float a = 0.f;
    for (int hc = 0; hc < 256; ++hc) a = fmaf(sWH[o * 256 + hc], sWE[hc * 27 + t], a);
    weff[p * (24 * 27) + j] = a;
  }
  if (tid < 24) {
    float a = b_head[tid];
    for (int hc = 0; hc < 256; ++hc) a = fmaf(sWH[tid * 256 + hc], sBE[hc], a);
    beff[p * 24 + tid] = a;
  }
}

// Phase A: compute the 40x24 region of gaussians (cy,cx,rgb) into LDS.
// Phase B: each thread gathers 2 vertically-adjacent pixels over the 10x9
// candidate window using ONLY the alpha test (provably equivalent to the
// reference's 5x5 window + alpha test), writes d_out directly. No atomics.
__global__ __launch_bounds__(256) void gather_kernel(
    const float* __restrict__ inp, const float* __restrict__ weff,
    const float* __restrict__ beff, float* __restrict__ out) {
  __shared__ float sW[WEFF_FLOATS];
  __shared__ float sB[BEFF_FLOATS];
  __shared__ float sCC[NG * 2];     // (cy, cx) pairs
  __shared__ float4 sCol[NG];       // (cr, cg, cb, 0)

  int tid = (int)threadIdx.x;
  for (int i = tid; i < WEFF_FLOATS; i += 256) sW[i] = weff[i];
  for (int i = tid; i < BEFF_FLOATS; i += 256) sB[i] = beff[i];
  __syncthreads();

  int bid = (int)blockIdx.x;
  int b = bid >> 7;                 // batch
  int t = bid & 127;                // 16 x-tiles, 8 y-tiles
  int TY = (t >> 4) * TSY;
  int TX = (t & 15) * TSX;
  const float* ib = inp + b * 3 * IH * IW;

  // ---- Phase A ----
  for (int gi = tid; gi < NG; gi += 256) {
    int gyr = gi / GRX, gxr = gi - gyr * GRX;
    int hh = TY - 3 + gyr, ww = TX - 3 + gxr;
    if ((unsigned)hh < GH && (unsigned)ww < GW) {
      int ph = hh & 1, pw_ = ww & 1, p = ph * 2 + pw_;
      int hs = hh >> 1, ws_ = ww >> 1;

      float in[27];
      #pragma unroll
      for (int cin = 0; cin < 3; ++cin) {
        #pragma unroll
        for (int ky = 0; ky < 3; ++ky) {
          int y = hs + ky - 1;
          #pragma unroll
          for (int kx = 0; kx < 3; ++kx) {
            int x = ws_ + kx - 1;
            float v = 0.f;
            if (y >= 0 && y < IH && x >= 0 && x < IW) v = ib[(cin * IH + y) * IW + x];
            in[cin * 9 + ky * 3 + kx] = v;
          }
        }
      }

      float pr[24];
      #pragma unroll
      for (int o = 0; o < 24; ++o) {
        float a = sB[p * 24 + o];
        const float* w = &sW[(p * 24 + o) * 27];
        #pragma unroll
        for (int k = 0; k < 27; ++k) a = fmaf(in[k], w[k], a);
        pr[o] = a;
      }

      float l0 = pr[5], l1 = pr[11], l2 = pr[17], l3 = pr[23];
      float m = fmaxf(fmaxf(l0, l1), fmaxf(l2, l3));
      float e0 = __expf(l0 - m), e1 = __expf(l1 - m);
      float e2 = __expf(l2 - m), e3 = __expf(l3 - m);
      float inv = 1.f / (e0 + e1 + e2 + e3);
      float w0 = e0 * inv, w1 = e1 * inv, w2 = e2 * inv, w3 = e3 * inv;
      float cr = w0 * pr[0] + w1 * pr[6] + w2 * pr[12] + w3 * pr[18];
      float cg = w0 * pr[1] + w1 * pr[7] + w2 * pr[13] + w3 * pr[19];
      float cb = w0 * pr[2] + w1 * pr[8] + w2 * pr[14] + w3 * pr[20];
      float ox = w0 * fast_tanh(pr[3]) + w1 * fast_tanh(pr[9]) +
                 w2 * fast_tanh(pr[15]) + w3 * fast_tanh(pr[21]);
      float oy = w0 * fast_tanh(pr[4]) + w1 * fast_tanh(pr[10]) +
                 w2 * fast_tanh(pr[16]) + w3 * fast_tanh(pr[22]);

      // reference-order coordinate math (w=h=128, W=H=gw=gh=256)
      float coordx = ((float)ww / 256.f) * 2.f - 1.f;
      float coordy = ((float)hh / 256.f) * 2.f - 1.f;
      float x_ndc = coordx + 2.f * ox / 128.f - 1.f / 256.f;
      float y_ndc = coordy + 2.f * oy / 128.f - 1.f / 256.f;
      float cx = 0.5f * ((x_ndc + 1.f) * 256.f - 1.f);
      float cy = 0.5f * ((y_ndc + 1.f) * 256.f - 1.f);

      sCC[gi * 2] = cy;
      sCC[gi * 2 + 1] = cx;
      sCol[gi] = float4{cr, cg, cb, 0.f};
    } else {
      sCC[gi * 2] = 1e9f;
      sCC[gi * 2 + 1] = 1e9f;
      sCol[gi] = float4{0.f, 0.f, 0.f, 0.f};
    }
  }
  __syncthreads();

  // ---- Phase B ----
  int pxl = tid & 15;
  int pyl = (tid >> 4) * 2;
  int px = TX + pxl, py = TY + pyl;
  float fpx = (float)px, fpy0 = (float)py, fpy1 = fpy0 + 1.f;

  float r0 = 0.f, g0 = 0.f, b0 = 0.f;
  float r1 = 0.f, g1 = 0.f, b1 = 0.f;

  for (int ry = 0; ry < 10; ++ry) {
    int gb = (pyl + ry) * GRX + pxl;
    #pragma unroll
    for (int rx = 0; rx < 9; ++rx) {
      int g = gb + rx;
      float cyv = sCC[g * 2];
      float cxv = sCC[g * 2 + 1];
      float dx = fpx - cxv;
      float dy0 = fpy0 - cyv;
      float dy1 = fpy1 - cyv;
      float dx2 = dx * dx;
      float rr0 = fmaf(dy0, dy0, dx2);
      float rr1 = fmaf(dy1, dy1, dx2);
      float a0 = fminf(0.999f, __expf(-2.f * rr0));
      float a1 = fminf(0.999f, __expf(-2.f * rr1));
      a0 = (a0 > (1.f / 255.f)) ? a0 : 0.f;
      a1 = (a1 > (1.f / 255.f)) ? a1 : 0.f;
      if (a0 + a1 > 0.f) {
        float4 c = sCol[g];
        r0 = fmaf(a0, c.x, r0); g0 = fmaf(a0, c.y, g0); b0 = fmaf(a0, c.z, b0);
        r1 = fmaf(a1, c.x, r1); g1 = fmaf(a1, c.y, g1); b1 = fmaf(a1, c.z, b1);
      }
    }
  }

  float* ob = out + b * 3 * GH * GW;
  int i0 = py * GW + px;
  int i1 = i0 + GW;
  ob[i0] = clamp01(r0);
  ob[GH * GW + i0] = clamp01(g0);
  ob[2 * GH * GW + i0] = clamp01(b0);
  ob[i1] = clamp01(r1);
  ob[GH * GW + i1] = clamp01(g1);
  ob[2 * GH * GW + i1] = clamp01(b1);
}

extern "C" void kernel_launch(void* const* d_in, const int* in_sizes, int n_in,
                              void* d_out, int out_size, void* d_ws, size_t ws_size,
                              hipStream_t stream) {
  const float* inp = (const float*)d_in[0];
  const float* w_enc = (const float*)d_in[1];
  const float* b_enc = (const float*)d_in[2];
  const float* w_head = (const float*)d_in[3];
  const float* b_head = (const float*)d_in[4];
  // d_in[5] = scale (int), hardcoded 2.

  float* weff = (float*)d_ws;
  float* beff = weff + WEFF_FLOATS;

  weff_kernel<<<4, 256, 0, stream>>>(w_enc, b_enc, w_head, b_head, weff, beff);

  // 4 batches x (256/16 x-tiles) x (256/32 y-tiles) = 512 blocks
  gather_kernel<<<NB * 128, 256, 0, stream>>>(inp, weff, beff, (float*)d_out);
}

// Round 7
// 100.755 us; speedup vs baseline: 3.6857x; 1.1212x over previous
//
#include <hip/hip_runtime.h>
#include <math.h>

#define NB 4
#define IH 128
#define IW 128
#define GH 256
#define GW 256
#define NGAUSS (NB * GH * GW)   // 262144

// d_ws layout (floats):
// [0, 2592)                weff [4][24][27]
// [2592, 2688)             beff [4][24]
// [2688, 2688+2N)          pos  float2[N]  (cy, cx)
// [.. +N)                  cr   [N]
// [.. +N)                  cg   [N]
// [.. +N)                  cb   [N]        total 2688 + 5N floats = 5.26 MB
#define WEFF_FLOATS (4 * 24 * 27)
#define BEFF_FLOATS (4 * 24)
#define POS_OFF 2688
#define CR_OFF (POS_OFF + 2 * NGAUSS)
#define CG_OFF (CR_OFF + NGAUSS)
#define CB_OFF (CG_OFF + NGAUSS)

// gather tiling: 16x16 pixel tile; candidate gaussians ww-px,hh-py in [-3,+4].
#define TSX 16
#define TSY 16
#define GR 24              // loaded region side (23 live + 1 dead for indexing)
#define NREG (GR * GR)     // 576
#define RR_MAX 2.770360f   // ln(255)/2 : alpha > 1/255  <=>  rr < RR_MAX
#define EXP2C (-2.8853900818f)  // -2/ln(2) : exp(-2rr) = exp2(EXP2C*rr)

__device__ __forceinline__ float fast_tanh(float x) {
  return 1.f - 2.f / (__expf(2.f * x) + 1.f);
}
__device__ __forceinline__ float clamp01(float v) {
  return fminf(1.f, fmaxf(0.f, v));
}

// One block per parity p: fold w_head x (pixel ops) x w_enc into
// W_eff[p][24][27], b_eff[p][24].
__global__ __launch_bounds__(256) void weff_kernel(
    const float* __restrict__ w_enc, const float* __restrict__ b_enc,
    const float* __restrict__ w_head, const float* __restrict__ b_head,
    float* __restrict__ weff, float* __restrict__ beff) {
  __shared__ float sWH[24 * 256];
  __shared__ float sWE[256 * 27];
  __shared__ float sBE[256];

  int tid = (int)threadIdx.x;
  int p = (int)blockIdx.x;          // p = ph*2 + pw
  int ph = p >> 1, pw = p & 1;

  for (int i = tid; i < 24 * 256; i += 256) sWH[i] = w_head[i];
  {
    int hc = tid;
    int ch = ((hc >> 2) << 4) + (2 * ph + ((hc >> 1) & 1)) * 4 + (2 * pw + (hc & 1));
    for (int t = 0; t < 27; ++t) sWE[hc * 27 + t] = w_enc[ch * 27 + t];
    sBE[hc] = b_enc[ch];
  }
  __syncthreads();

  for (int j = tid; j < 24 * 27; j += 256) {
    int o = j / 27, t = j % 27;
    float a = 0.f;
    for (int hc = 0; hc < 256; ++hc) a = fmaf(sWH[o * 256 + hc], sWE[hc * 27 + t], a);
    weff[p * (24 * 27) + j] = a;
  }
  if (tid < 24) {
    float a = b_head[tid];
    for (int hc = 0; hc < 256; ++hc) a = fmaf(sWH[tid * 256 + hc], sBE[hc], a);
    beff[p * 24 + tid] = a;
  }
}

// 512 blocks; each thread evaluates TWO same-parity gaussians (ww, ww+16),
// sharing the LDS weight reads. Writes pos/color planes (SoA) to ws.
__global__ __launch_bounds__(256) void gauss_kernel(
    const float* __restrict__ inp, const float* __restrict__ ws_ro,
    float* __restrict__ ws) {
  __shared__ float sW[4 * 24 * 28];   // k padded 27 -> 28 for float4 reads
  __shared__ float sB[BEFF_FLOATS];

  int tid = (int)threadIdx.x;
  for (int i = tid; i < 4 * 24 * 28; i += 256) {
    int row = i / 28, k = i - row * 28;   // row = p*24+o
    sW[i] = (k < 27) ? ws_ro[row * 27 + k] : 0.f;
  }
  for (int i = tid; i < BEFF_FLOATS; i += 256) sB[i] = ws_ro[WEFF_FLOATS + i];
  __syncthreads();

  int bid = (int)blockIdx.x;
  int b = bid >> 7;
  int t = bid & 127;                 // 16 y-tiles x 8 x-tiles of 16x32
  int TYg = (t >> 3) * 16;
  int TXg = (t & 7) * 32;
  int hh = TYg + (tid >> 4);
  int ww0 = TXg + (tid & 15);        // second gaussian at ww0+16 (same parity)
  int p = (hh & 1) * 2 + (ww0 & 1);
  int hs = hh >> 1, ws0 = ww0 >> 1;  // ws1 = ws0 + 8

  const float* ib = inp + b * 3 * IH * IW;
  float in0[28], in1[28];
  in0[27] = 0.f; in1[27] = 0.f;
  #pragma unroll
  for (int cin = 0; cin < 3; ++cin) {
    #pragma unroll
    for (int ky = 0; ky < 3; ++ky) {
      int y = hs + ky - 1;
      bool yok = (y >= 0 && y < IH);
      #pragma unroll
      for (int kx = 0; kx < 3; ++kx) {
        int x0 = ws0 + kx - 1;
        int x1 = x0 + 8;             // >= 7, never < 0
        float v0 = 0.f, v1 = 0.f;
        if (yok && x0 >= 0 && x0 < IW) v0 = ib[(cin * IH + y) * IW + x0];
        if (yok && x1 < IW) v1 = ib[(cin * IH + y) * IW + x1];
        in0[cin * 9 + ky * 3 + kx] = v0;
        in1[cin * 9 + ky * 3 + kx] = v1;
      }
    }
  }

  float a0[24], a1[24];
  #pragma unroll
  for (int o = 0; o < 24; ++o) { float bi = sB[p * 24 + o]; a0[o] = bi; a1[o] = bi; }
  #pragma unroll
  for (int o = 0; o < 24; ++o) {
    const float4* wrow = (const float4*)&sW[(p * 24 + o) * 28];
    #pragma unroll
    for (int kq = 0; kq < 7; ++kq) {
      float4 w = wrow[kq];
      a0[o] = fmaf(in0[kq * 4 + 0], w.x, a0[o]);
      a0[o] = fmaf(in0[kq * 4 + 1], w.y, a0[o]);
      a0[o] = fmaf(in0[kq * 4 + 2], w.z, a0[o]);
      a0[o] = fmaf(in0[kq * 4 + 3], w.w, a0[o]);
      a1[o] = fmaf(in1[kq * 4 + 0], w.x, a1[o]);
      a1[o] = fmaf(in1[kq * 4 + 1], w.y, a1[o]);
      a1[o] = fmaf(in1[kq * 4 + 2], w.z, a1[o]);
      a1[o] = fmaf(in1[kq * 4 + 3], w.w, a1[o]);
    }
  }

  float2* posP = (float2*)(ws + POS_OFF);

  #pragma unroll
  for (int which = 0; which < 2; ++which) {
    const float* pr = which ? a1 : a0;
    int ww = which ? (ww0 + 16) : ww0;

    float l0 = pr[5], l1 = pr[11], l2 = pr[17], l3 = pr[23];
    float m = fmaxf(fmaxf(l0, l1), fmaxf(l2, l3));
    float e0 = __expf(l0 - m), e1 = __expf(l1 - m);
    float e2 = __expf(l2 - m), e3 = __expf(l3 - m);
    float inv = 1.f / (e0 + e1 + e2 + e3);
    float w0 = e0 * inv, w1 = e1 * inv, w2 = e2 * inv, w3 = e3 * inv;
    float cr = w0 * pr[0] + w1 * pr[6] + w2 * pr[12] + w3 * pr[18];
    float cg = w0 * pr[1] + w1 * pr[7] + w2 * pr[13] + w3 * pr[19];
    float cb = w0 * pr[2] + w1 * pr[8] + w2 * pr[14] + w3 * pr[20];
    float ox = w0 * fast_tanh(pr[3]) + w1 * fast_tanh(pr[9]) +
               w2 * fast_tanh(pr[15]) + w3 * fast_tanh(pr[21]);
    float oy = w0 * fast_tanh(pr[4]) + w1 * fast_tanh(pr[10]) +
               w2 * fast_tanh(pr[16]) + w3 * fast_tanh(pr[22]);

    // reference-order coordinate math (w=h=128, W=H=gw=gh=256)
    float coordx = ((float)ww / 256.f) * 2.f - 1.f;
    float coordy = ((float)hh / 256.f) * 2.f - 1.f;
    float x_ndc = coordx + 2.f * ox / 128.f - 1.f / 256.f;
    float y_ndc = coordy + 2.f * oy / 128.f - 1.f / 256.f;
    float cx = 0.5f * ((x_ndc + 1.f) * 256.f - 1.f);
    float cy = 0.5f * ((y_ndc + 1.f) * 256.f - 1.f);

    int g = (b << 16) | (hh << 8) | ww;
    posP[g] = make_float2(cy, cx);
    ws[CR_OFF + g] = cr;
    ws[CG_OFF + g] = cg;
    ws[CB_OFF + g] = cb;
  }
}

// 1024 blocks; 16x16 px tile per block, 1 px/thread, exact 8x8 candidate
// window with rr-threshold test (== reference alpha test). No atomics.
__global__ __launch_bounds__(256) void gather_kernel(
    const float* __restrict__ ws, float* __restrict__ out) {
  __shared__ float2 sPos[NREG];
  __shared__ float4 sCol[NREG];

  int tid = (int)threadIdx.x;
  int bid = (int)blockIdx.x;
  int b = bid >> 8;
  int t = bid & 255;
  int TY = (t >> 4) * TSY;
  int TX = (t & 15) * TSX;
  const float2* posP = (const float2*)(ws + POS_OFF);

  for (int i = tid; i < NREG; i += 256) {
    int r = i / GR, c = i - r * GR;
    int hh = TY - 3 + r, ww = TX - 3 + c;
    if ((unsigned)hh < GH && (unsigned)ww < GW) {
      int g = (b << 16) | (hh << 8) | ww;
      sPos[i] = posP[g];
      sCol[i] = make_float4(ws[CR_OFF + g], ws[CG_OFF + g], ws[CB_OFF + g], 0.f);
    } else {
      sPos[i] = make_float2(1e9f, 1e9f);
      sCol[i] = make_float4(0.f, 0.f, 0.f, 0.f);
    }
  }
  __syncthreads();

  int pxl = tid & 15, pyl = tid >> 4;
  float fpx = (float)(TX + pxl), fpy = (float)(TY + pyl);
  float ar = 0.f, ag = 0.f, ab = 0.f;

  #pragma unroll
  for (int ry = 0; ry < 8; ++ry) {
    int base = (pyl + ry) * GR + pxl;
    #pragma unroll
    for (int rx = 0; rx < 8; ++rx) {
      float2 P = sPos[base + rx];
      float dy = fpy - P.x;
      float dx = fpx - P.y;
      float rr = fmaf(dy, dy, dx * dx);
      if (rr < RR_MAX) {
        float al = fminf(0.999f, exp2f(EXP2C * rr));
        float4 C = sCol[base + rx];
        ar = fmaf(al, C.x, ar);
        ag = fmaf(al, C.y, ag);
        ab = fmaf(al, C.z, ab);
      }
    }
  }

  float* ob = out + b * 3 * GH * GW;
  int i0 = (TY + pyl) * GW + (TX + pxl);
  ob[i0] = clamp01(ar);
  ob[GH * GW + i0] = clamp01(ag);
  ob[2 * GH * GW + i0] = clamp01(ab);
}

extern "C" void kernel_launch(void* const* d_in, const int* in_sizes, int n_in,
                              void* d_out, int out_size, void* d_ws, size_t ws_size,
                              hipStream_t stream) {
  const float* inp = (const float*)d_in[0];
  const float* w_enc = (const float*)d_in[1];
  const float* b_enc = (const float*)d_in[2];
  const float* w_head = (const float*)d_in[3];
  const float* b_head = (const float*)d_in[4];
  // d_in[5] = scale (int), hardcoded 2.

  float* ws = (float*)d_ws;
  float* weff = ws;                  // [0, 2592)
  float* beff = ws + WEFF_FLOATS;    // [2592, 2688)

  weff_kernel<<<4, 256, 0, stream>>>(w_enc, b_enc, w_head, b_head, weff, beff);

  gauss_kernel<<<512, 256, 0, stream>>>(inp, ws, ws);

  gather_kernel<<<NB * 256, 256, 0, stream>>>(ws, (float*)d_out);
}